// Round 9
// baseline (267.830 us; speedup 1.0000x reference)
//
#include <hip/hip_runtime.h>
#include <hip/hip_bf16.h>

#define HN 128
#define EPS 1e-5f
#define SCHUNK 256   // scan elements per block
#define NSLC 8       // row slices for the CSR fill == number of XCDs
#define NSUB 32      // edge sub-ranges (tickets) per slice

typedef __attribute__((ext_vector_type(8))) short bf16x8;
typedef __attribute__((ext_vector_type(4))) float f32x4;
typedef __attribute__((ext_vector_type(2))) float f32x2;

static __device__ inline short f2bs(float f) {
  __hip_bfloat16 h = __float2bfloat16(f);
  return *reinterpret_cast<short*>(&h);
}

static __device__ inline unsigned char f2fp8(float f) {
  unsigned p = __builtin_amdgcn_cvt_pk_fp8_f32(f, f, 0u, false);
  return (unsigned char)(p & 0xffu);
}

// ---------------- W f32 -> bf16 ----------------
__global__ __launch_bounds__(256) void wconv_k(const float* __restrict__ W,
                                               __hip_bfloat16* __restrict__ Wbf) {
  const int i = blockIdx.x * 256 + threadIdx.x;
  if (i < HN * HN) Wbf[i] = __float2bfloat16(W[i]);
}

// ---------------- GEMM via MFMA: m = relu(x @ W^T + b), fp8 out ----------
__global__ __launch_bounds__(256) void gemm_mfma_k(
    const float* __restrict__ x, const __hip_bfloat16* __restrict__ Wbf,
    const float* __restrict__ bias, unsigned char* __restrict__ m8,
    int nrows) {
  const int lane = threadIdx.x & 63;
  const int wv = threadIdx.x >> 6;
  const int r = lane & 15;
  const int kg = lane >> 4;

  const int row0 = blockIdx.x * 64 + wv * 16;
  if (row0 >= nrows) return;  // nrows % 16 == 0

  bf16x8 Bf[8][4];
#pragma unroll
  for (int n = 0; n < 8; ++n)
#pragma unroll
    for (int ks = 0; ks < 4; ++ks)
      Bf[n][ks] = *reinterpret_cast<const bf16x8*>(
          Wbf + (size_t)(n * 16 + r) * HN + ks * 32 + kg * 8);

  f32x4 acc[8];
#pragma unroll
  for (int n = 0; n < 8; ++n) {
    const float bv = bias[n * 16 + r];
    acc[n] = (f32x4){bv, bv, bv, bv};
  }

  bf16x8 Af[4];
  const float* xr = x + (size_t)(row0 + r) * HN + kg * 8;
#pragma unroll
  for (int ks = 0; ks < 4; ++ks) {
    const float4 f0 = *reinterpret_cast<const float4*>(xr + ks * 32);
    const float4 f1 = *reinterpret_cast<const float4*>(xr + ks * 32 + 4);
    bf16x8 a;
    a[0] = f2bs(f0.x); a[1] = f2bs(f0.y); a[2] = f2bs(f0.z); a[3] = f2bs(f0.w);
    a[4] = f2bs(f1.x); a[5] = f2bs(f1.y); a[6] = f2bs(f1.z); a[7] = f2bs(f1.w);
    Af[ks] = a;
  }

#pragma unroll
  for (int ks = 0; ks < 4; ++ks)
#pragma unroll
    for (int n = 0; n < 8; ++n)
      acc[n] = __builtin_amdgcn_mfma_f32_16x16x32_bf16(Af[ks], Bf[n][ks],
                                                       acc[n], 0, 0, 0);

#pragma unroll
  for (int n = 0; n < 8; ++n) {
#pragma unroll
    for (int reg = 0; reg < 4; ++reg) {
      const int rr = row0 + kg * 4 + reg;
      m8[(size_t)rr * HN + n * 16 + r] = f2fp8(fmaxf(acc[n][reg], 0.f));
    }
  }
}

// ---------------- degree histogram ----------------
__global__ void degree_k(const int* __restrict__ rows, int* __restrict__ deg,
                         int nedges) {
  for (int e = blockIdx.x * blockDim.x + threadIdx.x; e < nedges;
       e += gridDim.x * blockDim.x)
    atomicAdd(&deg[rows[e]], 1);
}

// ---------------- two-level scan ----------------
__global__ __launch_bounds__(SCHUNK) void blocksum_k(const int* __restrict__ deg,
                                                     int* __restrict__ bsum,
                                                     int n) {
  __shared__ int s[SCHUNK];
  const int i = blockIdx.x * SCHUNK + threadIdx.x;
  int v = (i < n) ? deg[i] : 0;
  s[threadIdx.x] = v;
  __syncthreads();
  for (int off = SCHUNK / 2; off > 0; off >>= 1) {
    if (threadIdx.x < off) s[threadIdx.x] += s[threadIdx.x + off];
    __syncthreads();
  }
  if (threadIdx.x == 0) bsum[blockIdx.x] = s[0];
}

__global__ __launch_bounds__(1024) void scan_bsums_k(int* __restrict__ bsum,
                                                     int* __restrict__ rowptr,
                                                     int nb, int n) {
  __shared__ int s[1024];
  const int t = threadIdx.x;
  int v = (t < nb) ? bsum[t] : 0;
  s[t] = v;
  __syncthreads();
  for (int off = 1; off < 1024; off <<= 1) {
    int u = 0;
    if (t >= off) u = s[t - off];
    __syncthreads();
    if (t >= off) s[t] += u;
    __syncthreads();
  }
  if (t < nb) bsum[t] = (t == 0) ? 0 : s[t - 1];
  if (t == 0) rowptr[n] = s[1023];
}

__global__ __launch_bounds__(SCHUNK) void rowptr_k(const int* __restrict__ deg,
                                                   const int* __restrict__ bsum,
                                                   int* __restrict__ rowptr,
                                                   int* __restrict__ cursor,
                                                   int n) {
  __shared__ int s[SCHUNK];
  const int i = blockIdx.x * SCHUNK + threadIdx.x;
  const int t = threadIdx.x;
  int v = (i < n) ? deg[i] : 0;
  s[t] = v;
  __syncthreads();
  for (int off = 1; off < SCHUNK; off <<= 1) {
    int u = 0;
    if (t >= off) u = s[t - off];
    __syncthreads();
    if (t >= off) s[t] += u;
    __syncthreads();
  }
  if (i < n) {
    const int excl = bsum[blockIdx.x] + s[t] - v;
    rowptr[i] = excl;
    cursor[i] = excl;
  }
}

// ---------------- XCD-pinned row-sliced CSR fill -------------------------
// Persistent 256-block kernel. Each block reads its physical XCD via
// s_getreg(HW_REG_XCC_ID) and drains the ticket queue of slice==xcc first
// (then steals from the other queues for guaranteed completion). All
// writers of slice s's csr span run on XCD s -> each 64B line dirty in ONE
// L2 -> written back once (R8: ~12 XCD-writers/line -> 74 MB WRITE_SIZE).
__global__ __launch_bounds__(1024) void fills_k(
    const int* __restrict__ rows, const int* __restrict__ cols,
    int* __restrict__ cursor, int* __restrict__ csr, int* __restrict__ qcur,
    int n, int nedges, int ch) {
  __shared__ int tk;
  int xcc = 0;
  asm volatile("s_getreg_b32 %0, hwreg(HW_REG_XCC_ID)" : "=s"(xcc));
  const int chunk = ((nedges + NSUB - 1) / NSUB + 3) & ~3;

  for (int d = 0; d < NSLC; ++d) {
    const int s = (xcc + d) & (NSLC - 1);
    const int lo = s * ch;
    const int hi = min(lo + ch, n);
    for (;;) {
      __syncthreads();
      if (threadIdx.x == 0) tk = atomicAdd(&qcur[s], 1);
      __syncthreads();
      const int k = tk;
      if (k >= NSUB) break;

      const int e0 = k * chunk;
      const int e1 = min(e0 + chunk, nedges);
      if (e0 >= e1) continue;
      const int4* rows4 = reinterpret_cast<const int4*>(rows + e0);
      const int4* cols4 = reinterpret_cast<const int4*>(cols + e0);
      const int ne4 = (e1 - e0) >> 2;
      for (int i = threadIdx.x; i < ne4; i += 1024) {
        const int4 rv = rows4[i];
        const int4 cv = cols4[i];
        if (rv.x >= lo && rv.x < hi) csr[atomicAdd(&cursor[rv.x], 1)] = cv.x;
        if (rv.y >= lo && rv.y < hi) csr[atomicAdd(&cursor[rv.y], 1)] = cv.y;
        if (rv.z >= lo && rv.z < hi) csr[atomicAdd(&cursor[rv.z], 1)] = cv.z;
        if (rv.w >= lo && rv.w < hi) csr[atomicAdd(&cursor[rv.w], 1)] = cv.w;
      }
      for (int e = e0 + (ne4 << 2) + threadIdx.x; e < e1; e += 1024) {
        const int r = rows[e];
        if (r >= lo && r < hi) csr[atomicAdd(&cursor[r], 1)] = cols[e];
      }
    }
  }
}

// ---------------- gather + avg + residual + RMSNorm (fused) ----------------
__global__ __launch_bounds__(256) void gather_k(
    const uint2* __restrict__ m2v, const int* __restrict__ rowptr,
    const int* __restrict__ csr, const float* __restrict__ x,
    const float* __restrict__ gamma, const float* __restrict__ beta,
    float* __restrict__ out, int nrows) {
  const int r = blockIdx.x * 4 + (threadIdx.x >> 6);
  if (r >= nrows) return;
  const int lane = threadIdx.x & 63;
  const int q = lane >> 4;   // quarter id
  const int l = lane & 15;   // col octet within quarter

  const int start = rowptr[r];
  const int end = rowptr[r + 1];
  float a[8] = {0.f, 0.f, 0.f, 0.f, 0.f, 0.f, 0.f, 0.f};

  for (int base = start; base < end; base += 64) {
    const int nv = min(64, end - base);
    const int c = (base + lane < end) ? csr[base + lane] : 0;
    for (int j = 0; j < nv; j += 4) {
      const int cc = __shfl(c, j + q);
      if (j + q < nv) {
        const uint2 u = m2v[cc * 16 + l];
#if __has_builtin(__builtin_amdgcn_cvt_pk_f32_fp8)
        const f32x2 f0 = __builtin_amdgcn_cvt_pk_f32_fp8(u.x, 0);
        const f32x2 f1 = __builtin_amdgcn_cvt_pk_f32_fp8(u.x, 1);
        const f32x2 f2 = __builtin_amdgcn_cvt_pk_f32_fp8(u.y, 0);
        const f32x2 f3 = __builtin_amdgcn_cvt_pk_f32_fp8(u.y, 1);
        a[0] += f0.x; a[1] += f0.y; a[2] += f1.x; a[3] += f1.y;
        a[4] += f2.x; a[5] += f2.y; a[6] += f3.x; a[7] += f3.y;
#else
        a[0] += __builtin_amdgcn_cvt_f32_fp8(u.x, 0);
        a[1] += __builtin_amdgcn_cvt_f32_fp8(u.x, 1);
        a[2] += __builtin_amdgcn_cvt_f32_fp8(u.x, 2);
        a[3] += __builtin_amdgcn_cvt_f32_fp8(u.x, 3);
        a[4] += __builtin_amdgcn_cvt_f32_fp8(u.y, 0);
        a[5] += __builtin_amdgcn_cvt_f32_fp8(u.y, 1);
        a[6] += __builtin_amdgcn_cvt_f32_fp8(u.y, 2);
        a[7] += __builtin_amdgcn_cvt_f32_fp8(u.y, 3);
#endif
      }
    }
  }

#pragma unroll
  for (int i = 0; i < 8; ++i) {
    a[i] += __shfl_xor(a[i], 16);
    a[i] += __shfl_xor(a[i], 32);
  }

  const int d = end - start;
  const float inv_d = (d > 0) ? 1.f / (float)d : 1.f;
  const float4 xv0 = *reinterpret_cast<const float4*>(x + (size_t)r * HN + 8 * l);
  const float4 xv1 = *reinterpret_cast<const float4*>(x + (size_t)r * HN + 8 * l + 4);
  float h[8];
  h[0] = xv0.x + a[0] * inv_d; h[1] = xv0.y + a[1] * inv_d;
  h[2] = xv0.z + a[2] * inv_d; h[3] = xv0.w + a[3] * inv_d;
  h[4] = xv1.x + a[4] * inv_d; h[5] = xv1.y + a[5] * inv_d;
  h[6] = xv1.z + a[6] * inv_d; h[7] = xv1.w + a[7] * inv_d;

  float ss = 0.f;
#pragma unroll
  for (int i = 0; i < 8; ++i) ss += h[i] * h[i];
  ss += __shfl_xor(ss, 1);
  ss += __shfl_xor(ss, 2);
  ss += __shfl_xor(ss, 4);
  ss += __shfl_xor(ss, 8);
  const float invrms = rsqrtf(ss * (1.f / HN) + EPS);

  if (q == 0) {
    const float4 gv0 = *reinterpret_cast<const float4*>(gamma + 8 * l);
    const float4 gv1 = *reinterpret_cast<const float4*>(gamma + 8 * l + 4);
    const float4 bv0 = *reinterpret_cast<const float4*>(beta + 8 * l);
    const float4 bv1 = *reinterpret_cast<const float4*>(beta + 8 * l + 4);
    float4 o0, o1;
    o0.x = h[0] * invrms * gv0.x + bv0.x;
    o0.y = h[1] * invrms * gv0.y + bv0.y;
    o0.z = h[2] * invrms * gv0.z + bv0.z;
    o0.w = h[3] * invrms * gv0.w + bv0.w;
    o1.x = h[4] * invrms * gv1.x + bv1.x;
    o1.y = h[5] * invrms * gv1.y + bv1.y;
    o1.z = h[6] * invrms * gv1.z + bv1.z;
    o1.w = h[7] * invrms * gv1.w + bv1.w;
    *reinterpret_cast<float4*>(out + (size_t)r * HN + 8 * l) = o0;
    *reinterpret_cast<float4*>(out + (size_t)r * HN + 8 * l + 4) = o1;
  }
}

extern "C" void kernel_launch(void* const* d_in, const int* in_sizes, int n_in,
                              void* d_out, int out_size, void* d_ws,
                              size_t ws_size, hipStream_t stream) {
  const float* x = (const float*)d_in[0];
  const float* W = (const float*)d_in[1];
  const float* b = (const float*)d_in[2];
  const float* gamma = (const float*)d_in[3];
  const float* beta = (const float*)d_in[4];
  const int* rows = (const int*)d_in[5];
  const int* cols = (const int*)d_in[6];
  float* out = (float*)d_out;

  const int N = in_sizes[0] / HN;  // 100000
  const int E = in_sizes[5];       // 1600000

  // ws layout: m_fp8 | Wbf | deg+qcur | rowptr | cursor | bsum | csr
  char* p = (char*)d_ws;
  unsigned char* m8 = (unsigned char*)p;
  p += ((size_t)N * HN + 255) & ~(size_t)255;
  __hip_bfloat16* Wbf = (__hip_bfloat16*)p;
  p += ((size_t)HN * HN * sizeof(__hip_bfloat16) + 255) & ~(size_t)255;
  int* deg = (int*)p;
  int* qcur = deg + N;  // 8 ints right after deg, covered by one memset
  p += ((size_t)(N + NSLC) * sizeof(int) + 255) & ~(size_t)255;
  int* rowptr = (int*)p;
  p += ((size_t)(N + 1) * sizeof(int) + 255) & ~(size_t)255;
  int* cursor = (int*)p;
  p += ((size_t)N * sizeof(int) + 255) & ~(size_t)255;
  int* bsum = (int*)p;
  p += ((size_t)2048 * sizeof(int) + 255) & ~(size_t)255;
  int* csr = (int*)p;

  hipMemsetAsync(deg, 0, (size_t)(N + NSLC) * sizeof(int), stream);

  const int nb = (N + SCHUNK - 1) / SCHUNK;  // 391
  const int ch = (N + NSLC - 1) / NSLC;      // 12500

  wconv_k<<<(HN * HN + 255) / 256, 256, 0, stream>>>(W, Wbf);
  gemm_mfma_k<<<(N + 63) / 64, 256, 0, stream>>>(x, Wbf, b, m8, N);
  degree_k<<<1024, 256, 0, stream>>>(rows, deg, E);
  blocksum_k<<<nb, SCHUNK, 0, stream>>>(deg, bsum, N);
  scan_bsums_k<<<1, 1024, 0, stream>>>(bsum, rowptr, nb, N);
  rowptr_k<<<nb, SCHUNK, 0, stream>>>(deg, bsum, rowptr, cursor, N);
  fills_k<<<256, 1024, 0, stream>>>(rows, cols, cursor, csr, qcur, N, E, ch);
  gather_k<<<(N + 3) / 4, 256, 0, stream>>>((const uint2*)m8, rowptr, csr, x,
                                            gamma, beta, out, N);
}

// Round 11
// 255.109 us; speedup vs baseline: 1.0499x; 1.0499x over previous
//
#include <hip/hip_runtime.h>
#include <hip/hip_bf16.h>

#define HN 128
#define EPS 1e-5f
#define SCHUNK 256   // scan elements per block
#define NSLC 8       // row slices for the CSR fill
#define NSUB 32      // edge sub-ranges per slice

typedef __attribute__((ext_vector_type(8))) short bf16x8;
typedef __attribute__((ext_vector_type(4))) float f32x4;
typedef __attribute__((ext_vector_type(2))) float f32x2;
typedef __attribute__((ext_vector_type(4))) int i32x4;  // builtin-compatible

static __device__ inline short f2bs(float f) {
  __hip_bfloat16 h = __float2bfloat16(f);
  return *reinterpret_cast<short*>(&h);
}

static __device__ inline unsigned char f2fp8(float f) {
  unsigned p = __builtin_amdgcn_cvt_pk_fp8_f32(f, f, 0u, false);
  return (unsigned char)(p & 0xffu);
}

// ---------------- W f32 -> bf16 ----------------
__global__ __launch_bounds__(256) void wconv_k(const float* __restrict__ W,
                                               __hip_bfloat16* __restrict__ Wbf) {
  const int i = blockIdx.x * 256 + threadIdx.x;
  if (i < HN * HN) Wbf[i] = __float2bfloat16(W[i]);
}

// ---------------- GEMM via MFMA: m = relu(x @ W^T + b), fp8 out ----------
__global__ __launch_bounds__(256) void gemm_mfma_k(
    const float* __restrict__ x, const __hip_bfloat16* __restrict__ Wbf,
    const float* __restrict__ bias, unsigned char* __restrict__ m8,
    int nrows) {
  const int lane = threadIdx.x & 63;
  const int wv = threadIdx.x >> 6;
  const int r = lane & 15;
  const int kg = lane >> 4;

  const int row0 = blockIdx.x * 64 + wv * 16;
  if (row0 >= nrows) return;  // nrows % 16 == 0

  bf16x8 Bf[8][4];
#pragma unroll
  for (int n = 0; n < 8; ++n)
#pragma unroll
    for (int ks = 0; ks < 4; ++ks)
      Bf[n][ks] = *reinterpret_cast<const bf16x8*>(
          Wbf + (size_t)(n * 16 + r) * HN + ks * 32 + kg * 8);

  f32x4 acc[8];
#pragma unroll
  for (int n = 0; n < 8; ++n) {
    const float bv = bias[n * 16 + r];
    acc[n] = (f32x4){bv, bv, bv, bv};
  }

  bf16x8 Af[4];
  const float* xr = x + (size_t)(row0 + r) * HN + kg * 8;
#pragma unroll
  for (int ks = 0; ks < 4; ++ks) {
    const float4 f0 = *reinterpret_cast<const float4*>(xr + ks * 32);
    const float4 f1 = *reinterpret_cast<const float4*>(xr + ks * 32 + 4);
    bf16x8 a;
    a[0] = f2bs(f0.x); a[1] = f2bs(f0.y); a[2] = f2bs(f0.z); a[3] = f2bs(f0.w);
    a[4] = f2bs(f1.x); a[5] = f2bs(f1.y); a[6] = f2bs(f1.z); a[7] = f2bs(f1.w);
    Af[ks] = a;
  }

#pragma unroll
  for (int ks = 0; ks < 4; ++ks)
#pragma unroll
    for (int n = 0; n < 8; ++n)
      acc[n] = __builtin_amdgcn_mfma_f32_16x16x32_bf16(Af[ks], Bf[n][ks],
                                                       acc[n], 0, 0, 0);

#pragma unroll
  for (int n = 0; n < 8; ++n) {
#pragma unroll
    for (int reg = 0; reg < 4; ++reg) {
      const int rr = row0 + kg * 4 + reg;
      m8[(size_t)rr * HN + n * 16 + r] = f2fp8(fmaxf(acc[n][reg], 0.f));
    }
  }
}

// ---------------- degree histogram ----------------
__global__ void degree_k(const int* __restrict__ rows, int* __restrict__ deg,
                         int nedges) {
  for (int e = blockIdx.x * blockDim.x + threadIdx.x; e < nedges;
       e += gridDim.x * blockDim.x)
    atomicAdd(&deg[__builtin_nontemporal_load(&rows[e])], 1);
}

// ---------------- two-level scan ----------------
__global__ __launch_bounds__(SCHUNK) void blocksum_k(const int* __restrict__ deg,
                                                     int* __restrict__ bsum,
                                                     int n) {
  __shared__ int s[SCHUNK];
  const int i = blockIdx.x * SCHUNK + threadIdx.x;
  int v = (i < n) ? deg[i] : 0;
  s[threadIdx.x] = v;
  __syncthreads();
  for (int off = SCHUNK / 2; off > 0; off >>= 1) {
    if (threadIdx.x < off) s[threadIdx.x] += s[threadIdx.x + off];
    __syncthreads();
  }
  if (threadIdx.x == 0) bsum[blockIdx.x] = s[0];
}

__global__ __launch_bounds__(1024) void scan_bsums_k(int* __restrict__ bsum,
                                                     int* __restrict__ rowptr,
                                                     int nb, int n) {
  __shared__ int s[1024];
  const int t = threadIdx.x;
  int v = (t < nb) ? bsum[t] : 0;
  s[t] = v;
  __syncthreads();
  for (int off = 1; off < 1024; off <<= 1) {
    int u = 0;
    if (t >= off) u = s[t - off];
    __syncthreads();
    if (t >= off) s[t] += u;
    __syncthreads();
  }
  if (t < nb) bsum[t] = (t == 0) ? 0 : s[t - 1];
  if (t == 0) rowptr[n] = s[1023];
}

__global__ __launch_bounds__(SCHUNK) void rowptr_k(const int* __restrict__ deg,
                                                   const int* __restrict__ bsum,
                                                   int* __restrict__ rowptr,
                                                   int* __restrict__ cursor,
                                                   int n) {
  __shared__ int s[SCHUNK];
  const int i = blockIdx.x * SCHUNK + threadIdx.x;
  const int t = threadIdx.x;
  int v = (i < n) ? deg[i] : 0;
  s[t] = v;
  __syncthreads();
  for (int off = 1; off < SCHUNK; off <<= 1) {
    int u = 0;
    if (t >= off) u = s[t - off];
    __syncthreads();
    if (t >= off) s[t] += u;
    __syncthreads();
  }
  if (i < n) {
    const int excl = bsum[blockIdx.x] + s[t] - v;
    rowptr[i] = excl;
    cursor[i] = excl;
  }
}

// ---------------- row-sliced CSR fill, (slice, subrange) grid -------------
// R8 structure + NON-TEMPORAL streaming reads (nt flag -> don't evict the
// dirty csr lines from L2). Theory: the 74 MB WRITE_SIZE (11x amplification)
// is partial csr lines written back each time streaming reads evict them
// (R9 falsified cross-XCD ping-pong: XCD-pinning left WRITE_SIZE unchanged).
__global__ __launch_bounds__(1024) void fills_k(
    const int* __restrict__ rows, const int* __restrict__ cols,
    int* __restrict__ cursor, int* __restrict__ csr, int n, int nedges,
    int ch) {
  const int s = blockIdx.x & (NSLC - 1);
  const int sub = blockIdx.x / NSLC;
  const int lo = s * ch;
  const int hi = min(lo + ch, n);
  const int chunk = ((nedges + NSUB - 1) / NSUB + 3) & ~3;
  const int e0 = sub * chunk;
  const int e1 = min(e0 + chunk, nedges);
  if (e0 >= e1) return;

  const i32x4* rows4 = reinterpret_cast<const i32x4*>(rows + e0);
  const i32x4* cols4 = reinterpret_cast<const i32x4*>(cols + e0);
  const int nE = e1 - e0;
  const int ne4 = nE >> 2;
  for (int i = threadIdx.x; i < ne4; i += 1024) {
    const i32x4 rv = __builtin_nontemporal_load(&rows4[i]);
    const i32x4 cv = __builtin_nontemporal_load(&cols4[i]);
    if (rv.x >= lo && rv.x < hi) csr[atomicAdd(&cursor[rv.x], 1)] = cv.x;
    if (rv.y >= lo && rv.y < hi) csr[atomicAdd(&cursor[rv.y], 1)] = cv.y;
    if (rv.z >= lo && rv.z < hi) csr[atomicAdd(&cursor[rv.z], 1)] = cv.z;
    if (rv.w >= lo && rv.w < hi) csr[atomicAdd(&cursor[rv.w], 1)] = cv.w;
  }
  for (int e = e0 + (ne4 << 2) + threadIdx.x; e < e1; e += 1024) {
    const int r = __builtin_nontemporal_load(&rows[e]);
    if (r >= lo && r < hi) csr[atomicAdd(&cursor[r], 1)] = cols[e];
  }
}

// ---------------- gather + avg + residual + RMSNorm (fused) ----------------
__global__ __launch_bounds__(256) void gather_k(
    const uint2* __restrict__ m2v, const int* __restrict__ rowptr,
    const int* __restrict__ csr, const float* __restrict__ x,
    const float* __restrict__ gamma, const float* __restrict__ beta,
    float* __restrict__ out, int nrows) {
  const int r = blockIdx.x * 4 + (threadIdx.x >> 6);
  if (r >= nrows) return;
  const int lane = threadIdx.x & 63;
  const int q = lane >> 4;   // quarter id
  const int l = lane & 15;   // col octet within quarter

  const int start = rowptr[r];
  const int end = rowptr[r + 1];
  float a[8] = {0.f, 0.f, 0.f, 0.f, 0.f, 0.f, 0.f, 0.f};

  for (int base = start; base < end; base += 64) {
    const int nv = min(64, end - base);
    const int c = (base + lane < end) ? csr[base + lane] : 0;
    for (int j = 0; j < nv; j += 4) {
      const int cc = __shfl(c, j + q);
      if (j + q < nv) {
        const uint2 u = m2v[cc * 16 + l];
#if __has_builtin(__builtin_amdgcn_cvt_pk_f32_fp8)
        const f32x2 f0 = __builtin_amdgcn_cvt_pk_f32_fp8(u.x, 0);
        const f32x2 f1 = __builtin_amdgcn_cvt_pk_f32_fp8(u.x, 1);
        const f32x2 f2 = __builtin_amdgcn_cvt_pk_f32_fp8(u.y, 0);
        const f32x2 f3 = __builtin_amdgcn_cvt_pk_f32_fp8(u.y, 1);
        a[0] += f0.x; a[1] += f0.y; a[2] += f1.x; a[3] += f1.y;
        a[4] += f2.x; a[5] += f2.y; a[6] += f3.x; a[7] += f3.y;
#else
        a[0] += __builtin_amdgcn_cvt_f32_fp8(u.x, 0);
        a[1] += __builtin_amdgcn_cvt_f32_fp8(u.x, 1);
        a[2] += __builtin_amdgcn_cvt_f32_fp8(u.x, 2);
        a[3] += __builtin_amdgcn_cvt_f32_fp8(u.x, 3);
        a[4] += __builtin_amdgcn_cvt_f32_fp8(u.y, 0);
        a[5] += __builtin_amdgcn_cvt_f32_fp8(u.y, 1);
        a[6] += __builtin_amdgcn_cvt_f32_fp8(u.y, 2);
        a[7] += __builtin_amdgcn_cvt_f32_fp8(u.y, 3);
#endif
      }
    }
  }

#pragma unroll
  for (int i = 0; i < 8; ++i) {
    a[i] += __shfl_xor(a[i], 16);
    a[i] += __shfl_xor(a[i], 32);
  }

  const int d = end - start;
  const float inv_d = (d > 0) ? 1.f / (float)d : 1.f;
  const float4 xv0 = *reinterpret_cast<const float4*>(x + (size_t)r * HN + 8 * l);
  const float4 xv1 = *reinterpret_cast<const float4*>(x + (size_t)r * HN + 8 * l + 4);
  float h[8];
  h[0] = xv0.x + a[0] * inv_d; h[1] = xv0.y + a[1] * inv_d;
  h[2] = xv0.z + a[2] * inv_d; h[3] = xv0.w + a[3] * inv_d;
  h[4] = xv1.x + a[4] * inv_d; h[5] = xv1.y + a[5] * inv_d;
  h[6] = xv1.z + a[6] * inv_d; h[7] = xv1.w + a[7] * inv_d;

  float ss = 0.f;
#pragma unroll
  for (int i = 0; i < 8; ++i) ss += h[i] * h[i];
  ss += __shfl_xor(ss, 1);
  ss += __shfl_xor(ss, 2);
  ss += __shfl_xor(ss, 4);
  ss += __shfl_xor(ss, 8);
  const float invrms = rsqrtf(ss * (1.f / HN) + EPS);

  if (q == 0) {
    const float4 gv0 = *reinterpret_cast<const float4*>(gamma + 8 * l);
    const float4 gv1 = *reinterpret_cast<const float4*>(gamma + 8 * l + 4);
    const float4 bv0 = *reinterpret_cast<const float4*>(beta + 8 * l);
    const float4 bv1 = *reinterpret_cast<const float4*>(beta + 8 * l + 4);
    float4 o0, o1;
    o0.x = h[0] * invrms * gv0.x + bv0.x;
    o0.y = h[1] * invrms * gv0.y + bv0.y;
    o0.z = h[2] * invrms * gv0.z + bv0.z;
    o0.w = h[3] * invrms * gv0.w + bv0.w;
    o1.x = h[4] * invrms * gv1.x + bv1.x;
    o1.y = h[5] * invrms * gv1.y + bv1.y;
    o1.z = h[6] * invrms * gv1.z + bv1.z;
    o1.w = h[7] * invrms * gv1.w + bv1.w;
    *reinterpret_cast<float4*>(out + (size_t)r * HN + 8 * l) = o0;
    *reinterpret_cast<float4*>(out + (size_t)r * HN + 8 * l + 4) = o1;
  }
}

extern "C" void kernel_launch(void* const* d_in, const int* in_sizes, int n_in,
                              void* d_out, int out_size, void* d_ws,
                              size_t ws_size, hipStream_t stream) {
  const float* x = (const float*)d_in[0];
  const float* W = (const float*)d_in[1];
  const float* b = (const float*)d_in[2];
  const float* gamma = (const float*)d_in[3];
  const float* beta = (const float*)d_in[4];
  const int* rows = (const int*)d_in[5];
  const int* cols = (const int*)d_in[6];
  float* out = (float*)d_out;

  const int N = in_sizes[0] / HN;  // 100000
  const int E = in_sizes[5];       // 1600000

  // ws layout: m_fp8 | Wbf | deg | rowptr | cursor | bsum | csr
  char* p = (char*)d_ws;
  unsigned char* m8 = (unsigned char*)p;
  p += ((size_t)N * HN + 255) & ~(size_t)255;
  __hip_bfloat16* Wbf = (__hip_bfloat16*)p;
  p += ((size_t)HN * HN * sizeof(__hip_bfloat16) + 255) & ~(size_t)255;
  int* deg = (int*)p;
  p += ((size_t)N * sizeof(int) + 255) & ~(size_t)255;
  int* rowptr = (int*)p;
  p += ((size_t)(N + 1) * sizeof(int) + 255) & ~(size_t)255;
  int* cursor = (int*)p;
  p += ((size_t)N * sizeof(int) + 255) & ~(size_t)255;
  int* bsum = (int*)p;
  p += ((size_t)2048 * sizeof(int) + 255) & ~(size_t)255;
  int* csr = (int*)p;

  (void)hipMemsetAsync(deg, 0, (size_t)N * sizeof(int), stream);

  const int nb = (N + SCHUNK - 1) / SCHUNK;  // 391
  const int ch = (N + NSLC - 1) / NSLC;      // 12500

  wconv_k<<<(HN * HN + 255) / 256, 256, 0, stream>>>(W, Wbf);
  gemm_mfma_k<<<(N + 63) / 64, 256, 0, stream>>>(x, Wbf, b, m8, N);
  degree_k<<<1024, 256, 0, stream>>>(rows, deg, E);
  blocksum_k<<<nb, SCHUNK, 0, stream>>>(deg, bsum, N);
  scan_bsums_k<<<1, 1024, 0, stream>>>(bsum, rowptr, nb, N);
  rowptr_k<<<nb, SCHUNK, 0, stream>>>(deg, bsum, rowptr, cursor, N);
  fills_k<<<NSLC * NSUB, 1024, 0, stream>>>(rows, cols, cursor, csr, N, E, ch);
  gather_k<<<(N + 3) / 4, 256, 0, stream>>>((const uint2*)m8, rowptr, csr, x,
                                            gamma, beta, out, N);
}